// Round 3
// baseline (366.111 us; speedup 1.0000x reference)
//
#include <hip/hip_runtime.h>
#include <stdint.h>

// Two-pass HashGrid encoder + 32->128(relu)->64 MLP, bf16 MFMA (16x16x32).
//
// Pass 1 (gather_kernel): level-major block groups -> the active level's
// (<=4 MB) table is L2-resident per XCD; features stored packed bf16x2
// (4 B/pt/level) in per-level planes of d_ws.
//
// Pass 2 (mlp_kernel): both GEMMs computed transposed so layer-1's C
// fragment is layer-2's B fragment (k-map kappa(g,j)=16*(j>>2)+4g+(j&3));
// W1^T/W2^T pre-packed with the same map by prep_kernel.
// R3 change: C-fragment stores go through a per-wave LDS transpose so each
// store instruction covers a contiguous 1 KB (8 full 128 B lines) — kills
// the partial-line write-allocate RMW that cost 558 MB FETCH + 130 MB extra
// WRITE in R2. Out stores are nontemporal (out is never re-read; keep L3
// for xw/tables).

typedef __attribute__((ext_vector_type(8))) __bf16 bf16x8;
typedef __attribute__((ext_vector_type(4))) float  f32x4;
typedef __attribute__((ext_vector_type(2))) float  f32x2;

#define NPTS   1048576
#define NTILES 65536   // NPTS / 16

// int(16 * (2048/16)**(l/15)) for l = 0..15
__device__ const unsigned kRES[16] = {16u,22u,30u,42u,58u,80u,111u,153u,
                                      212u,294u,406u,561u,776u,1072u,1482u,2048u};

__device__ __forceinline__ unsigned pack_bf16(float x, float y) {
  __bf16 a = (__bf16)x, b = (__bf16)y;
  unsigned short ua, ub;
  __builtin_memcpy(&ua, &a, 2);
  __builtin_memcpy(&ub, &b, 2);
  return (unsigned)ua | ((unsigned)ub << 16);
}

__global__ void prep_kernel(const float* __restrict__ W1, const float* __restrict__ W2,
                            short* __restrict__ w1p, short* __restrict__ w2p) {
  int tid = blockIdx.x * blockDim.x + threadIdx.x;   // 0..1535
  int l = tid & 63;
  int g = l >> 4;
  int c = l & 15;
  if (tid < 512) {
    int t = tid >> 6;
    bf16x8 v;
#pragma unroll
    for (int j = 0; j < 8; ++j)
      v[j] = (__bf16)W1[(8*g + j)*128 + 16*t + c];
    *(bf16x8*)(w1p + (size_t)(t*64 + l)*8) = v;
  } else if (tid < 1536) {
    int e = (tid - 512) >> 6;
    int mt = e >> 2, ks = e & 3;
    bf16x8 v;
#pragma unroll
    for (int j = 0; j < 8; ++j)
      v[j] = (__bf16)W2[(32*ks + 16*(j>>2) + 4*g + (j&3))*64 + 16*mt + c];
    *(bf16x8*)(w2p + (size_t)(e*64 + l)*8) = v;
  }
}

// ---------------- Pass 1: level-phased gather ----------------
__global__ __launch_bounds__(256) void gather_kernel(
    const float* __restrict__ coords, const float* __restrict__ tables,
    unsigned* __restrict__ xw)
{
  const int slot = blockIdx.x >> 10;
  const int lv = 15 - slot;                  // finest (biggest) levels first
  const unsigned R = kRES[lv];
  const float fR = (float)R;
  const unsigned RR = R * R;
  const unsigned Rm1 = R - 1u;
  const unsigned M = (lv >= 6) ? 0x7FFFFu : 0xFFFFFFFFu;
  const float* tb = tables + ((size_t)lv << 20);
  unsigned* xp = xw + ((size_t)lv << 20);

  int p0 = (blockIdx.x & 1023) * 1024 + threadIdx.x;
#pragma unroll
  for (int i = 0; i < 4; ++i) {              // 4 independent gather chains
    int p = p0 + (i << 8);
    float u0 = (coords[3*p+0] + 1.0f) * 0.5f;
    float u1 = (coords[3*p+1] + 1.0f) * 0.5f;
    float u2 = (coords[3*p+2] + 1.0f) * 0.5f;
    unsigned d0 = (unsigned)(int)(u0 * fR); if (d0 > Rm1) d0 = Rm1;
    unsigned d1 = (unsigned)(int)(u1 * fR); if (d1 > Rm1) d1 = Rm1;
    unsigned d2 = (unsigned)(int)(u2 * fR); if (d2 > Rm1) d2 = Rm1;
    unsigned idx = (d0*RR + d1*R + d2) & M;
    f32x2 f = *(const f32x2*)(tb + (size_t)idx*2u);
    xp[p] = pack_bf16(f.x, f.y);
  }
}

// ---------------- Pass 2: streaming MFMA MLP ----------------
__global__ __launch_bounds__(256, 4) void mlp_kernel(
    const unsigned* __restrict__ xw,
    const float* __restrict__ b1, const float* __restrict__ b2,
    const short* __restrict__ w1p, const short* __restrict__ w2p,
    float* __restrict__ out, int stride)
{
  const int l = threadIdx.x & 63;
  const int g = l >> 4;
  const int c = l & 15;
  const int w = threadIdx.x >> 6;

  // per-wave output transpose buffer: [16 pts][68 f] (pad 4 -> 16 B aligned
  // rows, bank-quad index (pt+c)%8 uniform -> no extra conflicts)
  __shared__ float obuf[4][16][68];

  bf16x8 w1f[8];
#pragma unroll
  for (int t = 0; t < 8; ++t)
    w1f[t] = *(const bf16x8*)(w1p + (size_t)(t*64 + l)*8);

  unsigned gx[4];
  auto prefetch = [&](int tile) {
    int p = tile*16 + c;
#pragma unroll
    for (int q = 0; q < 4; ++q)
      gx[q] = xw[((size_t)(4*g + q) << 20) + p];
  };

  int tile = blockIdx.x * 4 + w;
  prefetch(tile);
  while (true) {
    union { bf16x8 v; unsigned u[4]; } X;
#pragma unroll
    for (int q = 0; q < 4; ++q) X.u[q] = gx[q];
    bf16x8 xf = X.v;

    int cur = tile;
    tile += stride;
    if (tile < NTILES) prefetch(tile);   // overlap next reads with MFMA

    f32x4 h[8];
#pragma unroll
    for (int t = 0; t < 8; ++t) {
      h[t] = *(const f32x4*)(b1 + 16*t + 4*g);
      h[t] = __builtin_amdgcn_mfma_f32_16x16x32_bf16(w1f[t], xf, h[t], 0, 0, 0);
    }

    f32x4 o[4];
#pragma unroll
    for (int mt = 0; mt < 4; ++mt)
      o[mt] = *(const f32x4*)(b2 + 16*mt + 4*g);
#pragma unroll
    for (int ks = 0; ks < 4; ++ks) {
      bf16x8 bp;
#pragma unroll
      for (int j = 0; j < 8; ++j) {
        float v = h[2*ks + (j>>2)][j & 3];
        v = fmaxf(v, 0.0f);               // fused ReLU
        bp[j] = (__bf16)v;
      }
#pragma unroll
      for (int mt = 0; mt < 4; ++mt) {
        bf16x8 w2f = *(const bf16x8*)(w2p + (size_t)((mt*4 + ks)*64 + l)*8);
        o[mt] = __builtin_amdgcn_mfma_f32_16x16x32_bf16(w2f, bp, o[mt], 0, 0, 0);
      }
    }

    // --- LDS transpose: lane (g,c) holds out[pt=c][16mt+4g..+3] ---
    float (*ob)[68] = obuf[w];
#pragma unroll
    for (int mt = 0; mt < 4; ++mt)
      *(f32x4*)&ob[c][16*mt + 4*g] = o[mt];
    asm volatile("s_waitcnt lgkmcnt(0)" ::: "memory");   // wave-local fence
    f32x4 v[4];
#pragma unroll
    for (int s = 0; s < 4; ++s)
      v[s] = *(const f32x4*)&ob[4*s + g][4*c];
    asm volatile("" ::: "memory");
    // contiguous 1 KB per store instruction: lane (g,c) -> pt 4s+g, f 4c..4c+3
    float* op = out + (size_t)cur * 1024;
#pragma unroll
    for (int s = 0; s < 4; ++s)
      __builtin_nontemporal_store(v[s], (f32x4*)(op + (4*s + g)*64 + 4*c));

    if (tile >= NTILES) break;
  }
}

// ---------------- R1 fused kernel kept as fallback (ws too small) ----------
__global__ __launch_bounds__(256, 3) void hashgrid_mlp_kernel(
    const float* __restrict__ coords, const float* __restrict__ tables,
    const float* __restrict__ b1, const float* __restrict__ b2,
    const short* __restrict__ w1p, const short* __restrict__ w2p,
    float* __restrict__ out, int stride)
{
  const int l = threadIdx.x & 63;
  const int g = l >> 4;
  const int c = l & 15;

  unsigned Rq[4], RRq[4], Mq[4]; float fRq[4];
#pragma unroll
  for (int q = 0; q < 4; ++q) {
    int lv = 4*g + q;
    unsigned R = kRES[lv];
    Rq[q] = R; RRq[q] = R*R; fRq[q] = (float)R;
    Mq[q] = (lv >= 6) ? 0x7FFFFu : 0xFFFFFFFFu;
  }
  const float* tb = tables + ((size_t)g << 22);

  bf16x8 w1f[8];
#pragma unroll
  for (int t = 0; t < 8; ++t)
    w1f[t] = *(const bf16x8*)(w1p + (size_t)(t*64 + l)*8);

  f32x2 gx[4];
  auto prefetch = [&](int tile) {
    int p = tile*16 + c;
    float u0 = (coords[3*p+0] + 1.0f) * 0.5f;
    float u1 = (coords[3*p+1] + 1.0f) * 0.5f;
    float u2 = (coords[3*p+2] + 1.0f) * 0.5f;
#pragma unroll
    for (int q = 0; q < 4; ++q) {
      unsigned Rm1 = Rq[q] - 1u;
      unsigned d0 = (unsigned)(int)(u0 * fRq[q]); if (d0 > Rm1) d0 = Rm1;
      unsigned d1 = (unsigned)(int)(u1 * fRq[q]); if (d1 > Rm1) d1 = Rm1;
      unsigned d2 = (unsigned)(int)(u2 * fRq[q]); if (d2 > Rm1) d2 = Rm1;
      unsigned idx = (d0*RRq[q] + d1*Rq[q] + d2) & Mq[q];
      gx[q] = *(const f32x2*)(tb + ((size_t)q << 20) + (size_t)idx*2u);
    }
  };

  int tile = blockIdx.x * 4 + (threadIdx.x >> 6);
  prefetch(tile);
  while (true) {
    bf16x8 xf;
#pragma unroll
    for (int q = 0; q < 4; ++q) {
      xf[2*q]   = (__bf16)gx[q].x;
      xf[2*q+1] = (__bf16)gx[q].y;
    }
    int cur = tile;
    tile += stride;
    if (tile < NTILES) prefetch(tile);

    f32x4 h[8];
#pragma unroll
    for (int t = 0; t < 8; ++t) {
      h[t] = *(const f32x4*)(b1 + 16*t + 4*g);
      h[t] = __builtin_amdgcn_mfma_f32_16x16x32_bf16(w1f[t], xf, h[t], 0, 0, 0);
    }

    f32x4 o[4];
#pragma unroll
    for (int mt = 0; mt < 4; ++mt)
      o[mt] = *(const f32x4*)(b2 + 16*mt + 4*g);
#pragma unroll
    for (int ks = 0; ks < 4; ++ks) {
      bf16x8 bp;
#pragma unroll
      for (int j = 0; j < 8; ++j) {
        float v = h[2*ks + (j>>2)][j & 3];
        v = fmaxf(v, 0.0f);
        bp[j] = (__bf16)v;
      }
#pragma unroll
      for (int mt = 0; mt < 4; ++mt) {
        bf16x8 w2f = *(const bf16x8*)(w2p + (size_t)((mt*4 + ks)*64 + l)*8);
        o[mt] = __builtin_amdgcn_mfma_f32_16x16x32_bf16(w2f, bp, o[mt], 0, 0, 0);
      }
    }

    float* op = out + (size_t)(cur*16 + c)*64 + 4*g;
#pragma unroll
    for (int mt = 0; mt < 4; ++mt)
      *(f32x4*)(op + 16*mt) = o[mt];

    if (tile >= NTILES) break;
  }
}

extern "C" void kernel_launch(void* const* d_in, const int* in_sizes, int n_in,
                              void* d_out, int out_size, void* d_ws, size_t ws_size,
                              hipStream_t stream) {
  const float* coords = (const float*)d_in[0];
  const float* tables = (const float*)d_in[1];
  const float* W1     = (const float*)d_in[2];
  const float* b1     = (const float*)d_in[3];
  const float* W2     = (const float*)d_in[4];
  const float* b2     = (const float*)d_in[5];
  float* out = (float*)d_out;

  short* w1p = (short*)d_ws;          // 8 KB
  short* w2p = w1p + 4096;            // 16 KB
  prep_kernel<<<6, 256, 0, stream>>>(W1, W2, w1p, w2p);

  const size_t need = 32*1024 + (size_t)NPTS * 16 * 4;   // 64 MB + 32 KB
  if (ws_size >= need) {
    unsigned* xw = (unsigned*)((char*)d_ws + 32*1024);
    gather_kernel<<<16*1024, 256, 0, stream>>>(coords, tables, xw);
    const int blocks = 4096;          // 16384 waves x 4 tiles
    mlp_kernel<<<blocks, 256, 0, stream>>>(xw, b1, b2, w1p, w2p, out, blocks*4);
  } else {
    const int blocks = 2048;
    hashgrid_mlp_kernel<<<blocks, 256, 0, stream>>>(coords, tables, b1, b2,
                                                    w1p, w2p, out, blocks*4);
  }
}

// Round 4
// 206.556 us; speedup vs baseline: 1.7725x; 1.7725x over previous
//
#include <hip/hip_runtime.h>
#include <stdint.h>

// Two-pass HashGrid encoder + 32->128(relu)->64 MLP, bf16 MFMA (16x16x32).
//
// Pass 1 (gather_kernel, R4: XCD-partitioned): level l is processed ONLY by
// blocks on XCD l%8 (bid&7 == l%8 under round-robin dispatch), levels l and
// l+8 sequentially per XCD -> each table is pulled into exactly ONE L2 once
// (64 MB total EA traffic vs 8x broadcast before). Work is balanced: every
// level gathers all 1M points. Features stored packed bf16x2 in per-level
// planes of d_ws.
//
// Pass 2 (mlp_kernel): both GEMMs computed transposed so layer-1's C
// fragment is layer-2's B fragment (k-map kappa(g,j)=16*(j>>2)+4g+(j&3));
// W1^T/W2^T pre-packed with the same map by prep_kernel.
// R4 changes: (a) stores are LDS-transposed to contiguous 1 KB/instruction
// but PLAIN (R3's nontemporal streamed 64 B sectors -> W 516 MB, reverted);
// (b) each wave owns exactly 4 tiles, fully unrolled, ALL 16 xw loads
// issued up-front (16 outstanding vs depth-1 prefetch) to cover HBM latency.

typedef __attribute__((ext_vector_type(8))) __bf16 bf16x8;
typedef __attribute__((ext_vector_type(4))) float  f32x4;
typedef __attribute__((ext_vector_type(2))) float  f32x2;

#define NPTS   1048576
#define NTILES 65536   // NPTS / 16

// int(16 * (2048/16)**(l/15)) for l = 0..15
__device__ const unsigned kRES[16] = {16u,22u,30u,42u,58u,80u,111u,153u,
                                      212u,294u,406u,561u,776u,1072u,1482u,2048u};

__device__ __forceinline__ unsigned pack_bf16(float x, float y) {
  __bf16 a = (__bf16)x, b = (__bf16)y;
  unsigned short ua, ub;
  __builtin_memcpy(&ua, &a, 2);
  __builtin_memcpy(&ub, &b, 2);
  return (unsigned)ua | ((unsigned)ub << 16);
}

__global__ void prep_kernel(const float* __restrict__ W1, const float* __restrict__ W2,
                            short* __restrict__ w1p, short* __restrict__ w2p) {
  int tid = blockIdx.x * blockDim.x + threadIdx.x;   // 0..1535
  int l = tid & 63;
  int g = l >> 4;
  int c = l & 15;
  if (tid < 512) {
    int t = tid >> 6;
    bf16x8 v;
#pragma unroll
    for (int j = 0; j < 8; ++j)
      v[j] = (__bf16)W1[(8*g + j)*128 + 16*t + c];
    *(bf16x8*)(w1p + (size_t)(t*64 + l)*8) = v;
  } else if (tid < 1536) {
    int e = (tid - 512) >> 6;
    int mt = e >> 2, ks = e & 3;
    bf16x8 v;
#pragma unroll
    for (int j = 0; j < 8; ++j)
      v[j] = (__bf16)W2[(32*ks + 16*(j>>2) + 4*g + (j&3))*64 + 16*mt + c];
    *(bf16x8*)(w2p + (size_t)(e*64 + l)*8) = v;
  }
}

// ---------------- Pass 1: XCD-partitioned level gather ----------------
// grid = 16384 blocks. bid = j*8 + x: XCD x handles level x (j<1024) then
// level x+8 (j>=1024); chunk j&1023 covers 1024 points. Table of the active
// level is L2-resident on its XCD for its entire half-pass.
__global__ __launch_bounds__(256) void gather_kernel(
    const float* __restrict__ coords, const float* __restrict__ tables,
    unsigned* __restrict__ xw)
{
  const int x = blockIdx.x & 7;
  const int j = blockIdx.x >> 3;
  const int lv = x + ((j >= 1024) ? 8 : 0);
  const int chunk = j & 1023;

  const unsigned R = kRES[lv];
  const float fR = (float)R;
  const unsigned RR = R * R;
  const unsigned Rm1 = R - 1u;
  const unsigned M = (lv >= 6) ? 0x7FFFFu : 0xFFFFFFFFu;   // T=2^19 for lv>=6
  const float* tb = tables + ((size_t)lv << 20);
  unsigned* xp = xw + ((size_t)lv << 20);

  int p0 = chunk * 1024 + threadIdx.x;
#pragma unroll
  for (int i = 0; i < 4; ++i) {              // 4 independent gather chains
    int p = p0 + (i << 8);
    float u0 = (coords[3*p+0] + 1.0f) * 0.5f;
    float u1 = (coords[3*p+1] + 1.0f) * 0.5f;
    float u2 = (coords[3*p+2] + 1.0f) * 0.5f;
    unsigned d0 = (unsigned)(int)(u0 * fR); if (d0 > Rm1) d0 = Rm1;
    unsigned d1 = (unsigned)(int)(u1 * fR); if (d1 > Rm1) d1 = Rm1;
    unsigned d2 = (unsigned)(int)(u2 * fR); if (d2 > Rm1) d2 = Rm1;
    // uint32 wraparound matches reference (T = 2^19 divides 2^32 when masked)
    unsigned idx = (d0*RR + d1*R + d2) & M;
    f32x2 f = *(const f32x2*)(tb + (size_t)idx*2u);
    xp[p] = pack_bf16(f.x, f.y);
  }
}

// ---------------- Pass 2: streaming MFMA MLP ----------------
// 4096 blocks x 4 waves; wave owns tiles base + it*16384, it = 0..3 (exact).
__global__ __launch_bounds__(256, 4) void mlp_kernel(
    const unsigned* __restrict__ xw,
    const float* __restrict__ b1, const float* __restrict__ b2,
    const short* __restrict__ w1p, const short* __restrict__ w2p,
    float* __restrict__ out)
{
  const int l = threadIdx.x & 63;
  const int g = l >> 4;
  const int c = l & 15;
  const int w = threadIdx.x >> 6;

  __shared__ float obuf[4][16][68];   // per-wave transpose buffer

  bf16x8 w1f[8];
#pragma unroll
  for (int t = 0; t < 8; ++t)
    w1f[t] = *(const bf16x8*)(w1p + (size_t)(t*64 + l)*8);

  const int base = blockIdx.x * 4 + w;

  // Issue ALL 16 xw loads up-front: deep MLP, latency covered by 4 iters.
  unsigned gx[4][4];
#pragma unroll
  for (int it = 0; it < 4; ++it) {
    int p = (base + it*16384)*16 + c;
#pragma unroll
    for (int q = 0; q < 4; ++q)
      gx[it][q] = xw[((size_t)(4*g + q) << 20) + p];
  }

#pragma unroll
  for (int it = 0; it < 4; ++it) {
    union { bf16x8 v; unsigned u[4]; } X;
#pragma unroll
    for (int q = 0; q < 4; ++q) X.u[q] = gx[it][q];
    bf16x8 xf = X.v;

    f32x4 h[8];
#pragma unroll
    for (int t = 0; t < 8; ++t) {
      h[t] = *(const f32x4*)(b1 + 16*t + 4*g);
      h[t] = __builtin_amdgcn_mfma_f32_16x16x32_bf16(w1f[t], xf, h[t], 0, 0, 0);
    }

    f32x4 o[4];
#pragma unroll
    for (int mt = 0; mt < 4; ++mt)
      o[mt] = *(const f32x4*)(b2 + 16*mt + 4*g);
#pragma unroll
    for (int ks = 0; ks < 4; ++ks) {
      bf16x8 bp;
#pragma unroll
      for (int j = 0; j < 8; ++j) {
        float v = h[2*ks + (j>>2)][j & 3];
        v = fmaxf(v, 0.0f);               // fused ReLU
        bp[j] = (__bf16)v;
      }
#pragma unroll
      for (int mt = 0; mt < 4; ++mt) {
        bf16x8 w2f = *(const bf16x8*)(w2p + (size_t)((mt*4 + ks)*64 + l)*8);
        o[mt] = __builtin_amdgcn_mfma_f32_16x16x32_bf16(w2f, bp, o[mt], 0, 0, 0);
      }
    }

    // LDS transpose -> each store instruction covers contiguous 1 KB.
    float (*ob)[68] = obuf[w];
#pragma unroll
    for (int mt = 0; mt < 4; ++mt)
      *(f32x4*)&ob[c][16*mt + 4*g] = o[mt];
    asm volatile("s_waitcnt lgkmcnt(0)" ::: "memory");   // wave-local fence
    f32x4 v[4];
#pragma unroll
    for (int s = 0; s < 4; ++s)
      v[s] = *(const f32x4*)&ob[4*s + g][4*c];
    asm volatile("" ::: "memory");
    float* op = out + (size_t)(base + it*16384) * 1024;
#pragma unroll
    for (int s = 0; s < 4; ++s)
      *(f32x4*)(op + (4*s + g)*64 + 4*c) = v[s];   // plain stores (no nt)
  }
}

// ---------------- R1 fused kernel kept as fallback (ws too small) ----------
__global__ __launch_bounds__(256, 3) void hashgrid_mlp_kernel(
    const float* __restrict__ coords, const float* __restrict__ tables,
    const float* __restrict__ b1, const float* __restrict__ b2,
    const short* __restrict__ w1p, const short* __restrict__ w2p,
    float* __restrict__ out, int stride)
{
  const int l = threadIdx.x & 63;
  const int g = l >> 4;
  const int c = l & 15;

  unsigned Rq[4], RRq[4], Mq[4]; float fRq[4];
#pragma unroll
  for (int q = 0; q < 4; ++q) {
    int lv = 4*g + q;
    unsigned R = kRES[lv];
    Rq[q] = R; RRq[q] = R*R; fRq[q] = (float)R;
    Mq[q] = (lv >= 6) ? 0x7FFFFu : 0xFFFFFFFFu;
  }
  const float* tb = tables + ((size_t)g << 22);

  bf16x8 w1f[8];
#pragma unroll
  for (int t = 0; t < 8; ++t)
    w1f[t] = *(const bf16x8*)(w1p + (size_t)(t*64 + l)*8);

  f32x2 gx[4];
  auto prefetch = [&](int tile) {
    int p = tile*16 + c;
    float u0 = (coords[3*p+0] + 1.0f) * 0.5f;
    float u1 = (coords[3*p+1] + 1.0f) * 0.5f;
    float u2 = (coords[3*p+2] + 1.0f) * 0.5f;
#pragma unroll
    for (int q = 0; q < 4; ++q) {
      unsigned Rm1 = Rq[q] - 1u;
      unsigned d0 = (unsigned)(int)(u0 * fRq[q]); if (d0 > Rm1) d0 = Rm1;
      unsigned d1 = (unsigned)(int)(u1 * fRq[q]); if (d1 > Rm1) d1 = Rm1;
      unsigned d2 = (unsigned)(int)(u2 * fRq[q]); if (d2 > Rm1) d2 = Rm1;
      unsigned idx = (d0*RRq[q] + d1*Rq[q] + d2) & Mq[q];
      gx[q] = *(const f32x2*)(tb + ((size_t)q << 20) + (size_t)idx*2u);
    }
  };

  int tile = blockIdx.x * 4 + (threadIdx.x >> 6);
  prefetch(tile);
  while (true) {
    bf16x8 xf;
#pragma unroll
    for (int q = 0; q < 4; ++q) {
      xf[2*q]   = (__bf16)gx[q].x;
      xf[2*q+1] = (__bf16)gx[q].y;
    }
    int cur = tile;
    tile += stride;
    if (tile < NTILES) prefetch(tile);

    f32x4 h[8];
#pragma unroll
    for (int t = 0; t < 8; ++t) {
      h[t] = *(const f32x4*)(b1 + 16*t + 4*g);
      h[t] = __builtin_amdgcn_mfma_f32_16x16x32_bf16(w1f[t], xf, h[t], 0, 0, 0);
    }

    f32x4 o[4];
#pragma unroll
    for (int mt = 0; mt < 4; ++mt)
      o[mt] = *(const f32x4*)(b2 + 16*mt + 4*g);
#pragma unroll
    for (int ks = 0; ks < 4; ++ks) {
      bf16x8 bp;
#pragma unroll
      for (int j = 0; j < 8; ++j) {
        float v = h[2*ks + (j>>2)][j & 3];
        v = fmaxf(v, 0.0f);
        bp[j] = (__bf16)v;
      }
#pragma unroll
      for (int mt = 0; mt < 4; ++mt) {
        bf16x8 w2f = *(const bf16x8*)(w2p + (size_t)((mt*4 + ks)*64 + l)*8);
        o[mt] = __builtin_amdgcn_mfma_f32_16x16x32_bf16(w2f, bp, o[mt], 0, 0, 0);
      }
    }

    float* op = out + (size_t)(cur*16 + c)*64 + 4*g;
#pragma unroll
    for (int mt = 0; mt < 4; ++mt)
      *(f32x4*)(op + 16*mt) = o[mt];

    if (tile >= NTILES) break;
  }
}

extern "C" void kernel_launch(void* const* d_in, const int* in_sizes, int n_in,
                              void* d_out, int out_size, void* d_ws, size_t ws_size,
                              hipStream_t stream) {
  const float* coords = (const float*)d_in[0];
  const float* tables = (const float*)d_in[1];
  const float* W1     = (const float*)d_in[2];
  const float* b1     = (const float*)d_in[3];
  const float* W2     = (const float*)d_in[4];
  const float* b2     = (const float*)d_in[5];
  float* out = (float*)d_out;

  short* w1p = (short*)d_ws;          // 8 KB
  short* w2p = w1p + 4096;            // 16 KB
  prep_kernel<<<6, 256, 0, stream>>>(W1, W2, w1p, w2p);

  const size_t need = 32*1024 + (size_t)NPTS * 16 * 4;   // 64 MB + 32 KB
  if (ws_size >= need) {
    unsigned* xw = (unsigned*)((char*)d_ws + 32*1024);
    gather_kernel<<<16384, 256, 0, stream>>>(coords, tables, xw);
    mlp_kernel<<<4096, 256, 0, stream>>>(xw, b1, b2, w1p, w2p, out);
  } else {
    const int blocks = 2048;
    hashgrid_mlp_kernel<<<blocks, 256, 0, stream>>>(coords, tables, b1, b2,
                                                    w1p, w2p, out, blocks*4);
  }
}

// Round 5
// 194.095 us; speedup vs baseline: 1.8862x; 1.0642x over previous
//
#include <hip/hip_runtime.h>
#include <stdint.h>

// Two-pass HashGrid encoder + 32->128(relu)->64 MLP, bf16 MFMA (16x16x32).
//
// Pass 1 (gather_kernel, R5: load-balanced XCD-phased schedule):
//   Levels 5..15 all have ~4 MB tables ("hard": random gathers must hit L2);
//   levels 0..4 are <=1.6 MB ("easy"). R4 mapped level l -> XCD l%8, giving
//   XCDs 6,7 two hard levels (the critical path). R5 carves the 11264 hard
//   chunks (11 levels x 1024 chunks of 1K pts) into 8 contiguous runs of
//   1408 and the 5120 easy chunks into runs of 640: every XCD does exactly
//   1.375 hard levels + 0.625 easy, sequentially phased over <=3 tables so
//   each active table stays L2-resident on its XCD. A table shared by two
//   XCDs costs only +4 MB HBM.
//
// Pass 2 (mlp_kernel, unchanged from R4): both GEMMs computed transposed so
// layer-1's C fragment is layer-2's B fragment (k-map
// kappa(g,j)=16*(j>>2)+4g+(j&3)); W1^T/W2^T pre-packed with the same map by
// prep_kernel. All 16 xw loads issued up-front (4 exact iterations/wave);
// output goes through a per-wave LDS transpose so each store instruction
// covers a contiguous 1 KB (8 full 128 B lines) — plain stores (nt regressed
// in R3: 64 B-sector streaming inflated WRITE_SIZE 1.9x).

typedef __attribute__((ext_vector_type(8))) __bf16 bf16x8;
typedef __attribute__((ext_vector_type(4))) float  f32x4;
typedef __attribute__((ext_vector_type(2))) float  f32x2;

#define NPTS   1048576
#define NTILES 65536   // NPTS / 16

// int(16 * (2048/16)**(l/15)) for l = 0..15
__device__ const unsigned kRES[16] = {16u,22u,30u,42u,58u,80u,111u,153u,
                                      212u,294u,406u,561u,776u,1072u,1482u,2048u};

__device__ __forceinline__ unsigned pack_bf16(float x, float y) {
  __bf16 a = (__bf16)x, b = (__bf16)y;
  unsigned short ua, ub;
  __builtin_memcpy(&ua, &a, 2);
  __builtin_memcpy(&ub, &b, 2);
  return (unsigned)ua | ((unsigned)ub << 16);
}

__global__ void prep_kernel(const float* __restrict__ W1, const float* __restrict__ W2,
                            short* __restrict__ w1p, short* __restrict__ w2p) {
  int tid = blockIdx.x * blockDim.x + threadIdx.x;   // 0..1535
  int l = tid & 63;
  int g = l >> 4;
  int c = l & 15;
  if (tid < 512) {
    int t = tid >> 6;
    bf16x8 v;
#pragma unroll
    for (int j = 0; j < 8; ++j)
      v[j] = (__bf16)W1[(8*g + j)*128 + 16*t + c];
    *(bf16x8*)(w1p + (size_t)(t*64 + l)*8) = v;
  } else if (tid < 1536) {
    int e = (tid - 512) >> 6;
    int mt = e >> 2, ks = e & 3;
    bf16x8 v;
#pragma unroll
    for (int j = 0; j < 8; ++j)
      v[j] = (__bf16)W2[(32*ks + 16*(j>>2) + 4*g + (j&3))*64 + 16*mt + c];
    *(bf16x8*)(w2p + (size_t)(e*64 + l)*8) = v;
  }
}

// ---------------- Pass 1: balanced XCD-phased level gather ----------------
// grid = 16384 blocks; bid = j*8 + xcd (round-robin dispatch -> bid&7 = XCD).
// Per XCD: j in [0,2048). j<1408: hard chunks (levels 5..15), contiguous run
// xcd*1408+j. j>=1408: easy chunks (levels 0..4), run xcd*640+(j-1408).
__global__ __launch_bounds__(256) void gather_kernel(
    const float* __restrict__ coords, const float* __restrict__ tables,
    unsigned* __restrict__ xw)
{
  const int xcd = blockIdx.x & 7;
  const int j   = blockIdx.x >> 3;
  int lv, chunk;
  if (j < 1408) {
    int ghi = xcd * 1408 + j;          // 0..11263
    lv = 5 + (ghi >> 10);              // 5..15
    chunk = ghi & 1023;
  } else {
    int gei = xcd * 640 + (j - 1408);  // 0..5119
    lv = gei >> 10;                    // 0..4
    chunk = gei & 1023;
  }

  const unsigned R = kRES[lv];
  const float fR = (float)R;
  const unsigned RR = R * R;
  const unsigned Rm1 = R - 1u;
  // levels >= 6: T = 2^19 (mask); levels <= 5: idx < R^3 = T already.
  const unsigned M = (lv >= 6) ? 0x7FFFFu : 0xFFFFFFFFu;
  const float* tb = tables + ((size_t)lv << 20);
  unsigned* xp = xw + ((size_t)lv << 20);

  int p0 = chunk * 1024 + threadIdx.x;
#pragma unroll
  for (int i = 0; i < 4; ++i) {        // 4 independent gather chains
    int p = p0 + (i << 8);
    float u0 = (coords[3*p+0] + 1.0f) * 0.5f;
    float u1 = (coords[3*p+1] + 1.0f) * 0.5f;
    float u2 = (coords[3*p+2] + 1.0f) * 0.5f;
    unsigned d0 = (unsigned)(int)(u0 * fR); if (d0 > Rm1) d0 = Rm1;
    unsigned d1 = (unsigned)(int)(u1 * fR); if (d1 > Rm1) d1 = Rm1;
    unsigned d2 = (unsigned)(int)(u2 * fR); if (d2 > Rm1) d2 = Rm1;
    // uint32 wraparound matches reference (T = 2^19 divides 2^32 when masked)
    unsigned idx = (d0*RR + d1*R + d2) & M;
    f32x2 f = *(const f32x2*)(tb + (size_t)idx*2u);
    xp[p] = pack_bf16(f.x, f.y);
  }
}

// ---------------- Pass 2: streaming MFMA MLP (unchanged from R4) ----------
__global__ __launch_bounds__(256, 4) void mlp_kernel(
    const unsigned* __restrict__ xw,
    const float* __restrict__ b1, const float* __restrict__ b2,
    const short* __restrict__ w1p, const short* __restrict__ w2p,
    float* __restrict__ out)
{
  const int l = threadIdx.x & 63;
  const int g = l >> 4;
  const int c = l & 15;
  const int w = threadIdx.x >> 6;

  __shared__ float obuf[4][16][68];   // per-wave transpose buffer

  bf16x8 w1f[8];
#pragma unroll
  for (int t = 0; t < 8; ++t)
    w1f[t] = *(const bf16x8*)(w1p + (size_t)(t*64 + l)*8);

  const int base = blockIdx.x * 4 + w;

  unsigned gx[4][4];
#pragma unroll
  for (int it = 0; it < 4; ++it) {
    int p = (base + it*16384)*16 + c;
#pragma unroll
    for (int q = 0; q < 4; ++q)
      gx[it][q] = xw[((size_t)(4*g + q) << 20) + p];
  }

#pragma unroll
  for (int it = 0; it < 4; ++it) {
    union { bf16x8 v; unsigned u[4]; } X;
#pragma unroll
    for (int q = 0; q < 4; ++q) X.u[q] = gx[it][q];
    bf16x8 xf = X.v;

    f32x4 h[8];
#pragma unroll
    for (int t = 0; t < 8; ++t) {
      h[t] = *(const f32x4*)(b1 + 16*t + 4*g);
      h[t] = __builtin_amdgcn_mfma_f32_16x16x32_bf16(w1f[t], xf, h[t], 0, 0, 0);
    }

    f32x4 o[4];
#pragma unroll
    for (int mt = 0; mt < 4; ++mt)
      o[mt] = *(const f32x4*)(b2 + 16*mt + 4*g);
#pragma unroll
    for (int ks = 0; ks < 4; ++ks) {
      bf16x8 bp;
#pragma unroll
      for (int j = 0; j < 8; ++j) {
        float v = h[2*ks + (j>>2)][j & 3];
        v = fmaxf(v, 0.0f);               // fused ReLU
        bp[j] = (__bf16)v;
      }
#pragma unroll
      for (int mt = 0; mt < 4; ++mt) {
        bf16x8 w2f = *(const bf16x8*)(w2p + (size_t)((mt*4 + ks)*64 + l)*8);
        o[mt] = __builtin_amdgcn_mfma_f32_16x16x32_bf16(w2f, bp, o[mt], 0, 0, 0);
      }
    }

    // LDS transpose -> each store instruction covers contiguous 1 KB.
    float (*ob)[68] = obuf[w];
#pragma unroll
    for (int mt = 0; mt < 4; ++mt)
      *(f32x4*)&ob[c][16*mt + 4*g] = o[mt];
    asm volatile("s_waitcnt lgkmcnt(0)" ::: "memory");   // wave-local fence
    f32x4 v[4];
#pragma unroll
    for (int s = 0; s < 4; ++s)
      v[s] = *(const f32x4*)&ob[4*s + g][4*c];
    asm volatile("" ::: "memory");
    float* op = out + (size_t)(base + it*16384) * 1024;
#pragma unroll
    for (int s = 0; s < 4; ++s)
      *(f32x4*)(op + (4*s + g)*64 + 4*c) = v[s];   // plain stores

    if (it < 3) asm volatile("s_waitcnt lgkmcnt(0)" ::: "memory");
  }
}

// ---------------- R1 fused kernel kept as fallback (ws too small) ----------
__global__ __launch_bounds__(256, 3) void hashgrid_mlp_kernel(
    const float* __restrict__ coords, const float* __restrict__ tables,
    const float* __restrict__ b1, const float* __restrict__ b2,
    const short* __restrict__ w1p, const short* __restrict__ w2p,
    float* __restrict__ out, int stride)
{
  const int l = threadIdx.x & 63;
  const int g = l >> 4;
  const int c = l & 15;

  unsigned Rq[4], RRq[4], Mq[4]; float fRq[4];
#pragma unroll
  for (int q = 0; q < 4; ++q) {
    int lv = 4*g + q;
    unsigned R = kRES[lv];
    Rq[q] = R; RRq[q] = R*R; fRq[q] = (float)R;
    Mq[q] = (lv >= 6) ? 0x7FFFFu : 0xFFFFFFFFu;
  }
  const float* tb = tables + ((size_t)g << 22);

  bf16x8 w1f[8];
#pragma unroll
  for (int t = 0; t < 8; ++t)
    w1f[t] = *(const bf16x8*)(w1p + (size_t)(t*64 + l)*8);

  f32x2 gx[4];
  auto prefetch = [&](int tile) {
    int p = tile*16 + c;
    float u0 = (coords[3*p+0] + 1.0f) * 0.5f;
    float u1 = (coords[3*p+1] + 1.0f) * 0.5f;
    float u2 = (coords[3*p+2] + 1.0f) * 0.5f;
#pragma unroll
    for (int q = 0; q < 4; ++q) {
      unsigned Rm1 = Rq[q] - 1u;
      unsigned d0 = (unsigned)(int)(u0 * fRq[q]); if (d0 > Rm1) d0 = Rm1;
      unsigned d1 = (unsigned)(int)(u1 * fRq[q]); if (d1 > Rm1) d1 = Rm1;
      unsigned d2 = (unsigned)(int)(u2 * fRq[q]); if (d2 > Rm1) d2 = Rm1;
      unsigned idx = (d0*RRq[q] + d1*Rq[q] + d2) & Mq[q];
      gx[q] = *(const f32x2*)(tb + ((size_t)q << 20) + (size_t)idx*2u);
    }
  };

  int tile = blockIdx.x * 4 + (threadIdx.x >> 6);
  prefetch(tile);
  while (true) {
    bf16x8 xf;
#pragma unroll
    for (int q = 0; q < 4; ++q) {
      xf[2*q]   = (__bf16)gx[q].x;
      xf[2*q+1] = (__bf16)gx[q].y;
    }
    int cur = tile;
    tile += stride;
    if (tile < NTILES) prefetch(tile);

    f32x4 h[8];
#pragma unroll
    for (int t = 0; t < 8; ++t) {
      h[t] = *(const f32x4*)(b1 + 16*t + 4*g);
      h[t] = __builtin_amdgcn_mfma_f32_16x16x32_bf16(w1f[t], xf, h[t], 0, 0, 0);
    }

    f32x4 o[4];
#pragma unroll
    for (int mt = 0; mt < 4; ++mt)
      o[mt] = *(const f32x4*)(b2 + 16*mt + 4*g);
#pragma unroll
    for (int ks = 0; ks < 4; ++ks) {
      bf16x8 bp;
#pragma unroll
      for (int j = 0; j < 8; ++j) {
        float v = h[2*ks + (j>>2)][j & 3];
        v = fmaxf(v, 0.0f);
        bp[j] = (__bf16)v;
      }
#pragma unroll
      for (int mt = 0; mt < 4; ++mt) {
        bf16x8 w2f = *(const bf16x8*)(w2p + (size_t)((mt*4 + ks)*64 + l)*8);
        o[mt] = __builtin_amdgcn_mfma_f32_16x16x32_bf16(w2f, bp, o[mt], 0, 0, 0);
      }
    }

    float* op = out + (size_t)(cur*16 + c)*64 + 4*g;
#pragma unroll
    for (int mt = 0; mt < 4; ++mt)
      *(f32x4*)(op + 16*mt) = o[mt];

    if (tile >= NTILES) break;
  }
}

extern "C" void kernel_launch(void* const* d_in, const int* in_sizes, int n_in,
                              void* d_out, int out_size, void* d_ws, size_t ws_size,
                              hipStream_t stream) {
  const float* coords = (const float*)d_in[0];
  const float* tables = (const float*)d_in[1];
  const float* W1     = (const float*)d_in[2];
  const float* b1     = (const float*)d_in[3];
  const float* W2     = (const float*)d_in[4];
  const float* b2     = (const float*)d_in[5];
  float* out = (float*)d_out;

  short* w1p = (short*)d_ws;          // 8 KB
  short* w2p = w1p + 4096;            // 16 KB
  prep_kernel<<<6, 256, 0, stream>>>(W1, W2, w1p, w2p);

  const size_t need = 32*1024 + (size_t)NPTS * 16 * 4;   // 64 MB + 32 KB
  if (ws_size >= need) {
    unsigned* xw = (unsigned*)((char*)d_ws + 32*1024);
    gather_kernel<<<16384, 256, 0, stream>>>(coords, tables, xw);
    mlp_kernel<<<4096, 256, 0, stream>>>(xw, b1, b2, w1p, w2p, out);
  } else {
    const int blocks = 2048;
    hashgrid_mlp_kernel<<<blocks, 256, 0, stream>>>(coords, tables, b1, b2,
                                                    w1p, w2p, out, blocks*4);
  }
}

// Round 6
// 188.285 us; speedup vs baseline: 1.9444x; 1.0309x over previous
//
#include <hip/hip_runtime.h>
#include <stdint.h>

// Three-stage HashGrid encoder + 32->128(relu)->64 MLP, bf16 MFMA (16x16x32).
//
// Stage 0 (tconv_prep_kernel): converts all 16 hash tables fp32x2 -> packed
// bf16x2 (64 MB -> 32 MB in d_ws) and packs W1^T/W2^T MFMA fragments.
// Converting tables to bf16 FIRST is bit-identical to casting gathered
// features later (same rounding), and halves each hard table to 2 MB ->
// comfortably L2-resident next to streaming coords/xw traffic (R5's 4 MB
// tables exactly filled the per-XCD L2 and thrashed against the streams).
//
// Stage 1 (gather_kernel, R5 balanced XCD-phased schedule): levels 5..15
// ("hard", 2 MB bf16 tables) carved into 8 contiguous runs of 1408 chunks,
// levels 0..4 ("easy") into runs of 640 -> every XCD does 1.375 hard levels
// sequentially, active table L2-resident. Gather = 4 B load + 4 B store.
//
// Stage 2 (mlp_kernel): both GEMMs computed transposed so layer-1's C
// fragment is layer-2's B fragment (k-map kappa(g,j)=16*(j>>2)+4g+(j&3));
// W1^T/W2^T pre-packed with the same map. All 16 xw loads issued up-front
// (4 exact iterations/wave); output goes through a per-wave LDS transpose so
// each store instruction covers a contiguous 1 KB (8 full 128 B lines) —
// plain stores (nontemporal regressed: 64 B-sector streaming, W x1.9).

typedef __attribute__((ext_vector_type(8))) __bf16 bf16x8;
typedef __attribute__((ext_vector_type(4))) float  f32x4;
typedef __attribute__((ext_vector_type(2))) float  f32x2;

#define NPTS   1048576
#define NTILES 65536   // NPTS / 16

// int(16 * (2048/16)**(l/15)) for l = 0..15
__device__ const unsigned kRES[16] = {16u,22u,30u,42u,58u,80u,111u,153u,
                                      212u,294u,406u,561u,776u,1072u,1482u,2048u};

__device__ __forceinline__ unsigned pack_bf16(float x, float y) {
  __bf16 a = (__bf16)x, b = (__bf16)y;
  unsigned short ua, ub;
  __builtin_memcpy(&ua, &a, 2);
  __builtin_memcpy(&ub, &b, 2);
  return (unsigned)ua | ((unsigned)ub << 16);
}

// ---------------- Stage 0: table bf16 conversion + weight prep ----------
// blocks 0..8191: convert 4 entries/thread (8192*256*4 = 16*2^19 entries).
// blocks 8192..8197: pack W1/W2 fragments (tid 0..1535).
__global__ __launch_bounds__(256) void tconv_prep_kernel(
    const float* __restrict__ tables,
    const float* __restrict__ W1, const float* __restrict__ W2,
    unsigned* __restrict__ tb2, short* __restrict__ w1p, short* __restrict__ w2p)
{
  if (blockIdx.x < 8192) {
    int e0 = (blockIdx.x * 256 + threadIdx.x) * 4;
#pragma unroll
    for (int i = 0; i < 4; ++i) {
      int e = e0 + i;
      f32x2 f = *(const f32x2*)(tables + (size_t)e * 2);
      tb2[e] = pack_bf16(f.x, f.y);
    }
    return;
  }
  int tid = (blockIdx.x - 8192) * 256 + threadIdx.x;   // 0..1535
  int l = tid & 63;
  int g = l >> 4;
  int c = l & 15;
  if (tid < 512) {
    int t = tid >> 6;
    bf16x8 v;
#pragma unroll
    for (int j = 0; j < 8; ++j)
      v[j] = (__bf16)W1[(8*g + j)*128 + 16*t + c];
    *(bf16x8*)(w1p + (size_t)(t*64 + l)*8) = v;
  } else if (tid < 1536) {
    int e = (tid - 512) >> 6;
    int mt = e >> 2, ks = e & 3;
    bf16x8 v;
#pragma unroll
    for (int j = 0; j < 8; ++j)
      v[j] = (__bf16)W2[(32*ks + 16*(j>>2) + 4*g + (j&3))*64 + 16*mt + c];
    *(bf16x8*)(w2p + (size_t)(e*64 + l)*8) = v;
  }
}

// ---------------- Stage 1: balanced XCD-phased level gather ----------------
// grid = 16384 blocks; bid = j*8 + xcd (round-robin dispatch -> bid&7 = XCD).
// Per XCD: j in [0,2048). j<1408: hard chunks (levels 5..15), contiguous run
// xcd*1408+j. j>=1408: easy chunks (levels 0..4), run xcd*640+(j-1408).
__global__ __launch_bounds__(256) void gather_kernel(
    const float* __restrict__ coords, const unsigned* __restrict__ tb2,
    unsigned* __restrict__ xw)
{
  const int xcd = blockIdx.x & 7;
  const int j   = blockIdx.x >> 3;
  int lv, chunk;
  if (j < 1408) {
    int ghi = xcd * 1408 + j;          // 0..11263
    lv = 5 + (ghi >> 10);              // 5..15
    chunk = ghi & 1023;
  } else {
    int gei = xcd * 640 + (j - 1408);  // 0..5119
    lv = gei >> 10;                    // 0..4
    chunk = gei & 1023;
  }

  const unsigned R = kRES[lv];
  const float fR = (float)R;
  const unsigned RR = R * R;
  const unsigned Rm1 = R - 1u;
  // levels >= 6: T = 2^19 (mask); levels <= 5: idx < R^3 = T already.
  const unsigned M = (lv >= 6) ? 0x7FFFFu : 0xFFFFFFFFu;
  const unsigned* tb = tb2 + ((size_t)lv << 19);
  unsigned* xp = xw + ((size_t)lv << 20);

  int p0 = chunk * 1024 + threadIdx.x;
#pragma unroll
  for (int i = 0; i < 4; ++i) {        // 4 independent gather chains
    int p = p0 + (i << 8);
    float u0 = (coords[3*p+0] + 1.0f) * 0.5f;
    float u1 = (coords[3*p+1] + 1.0f) * 0.5f;
    float u2 = (coords[3*p+2] + 1.0f) * 0.5f;
    unsigned d0 = (unsigned)(int)(u0 * fR); if (d0 > Rm1) d0 = Rm1;
    unsigned d1 = (unsigned)(int)(u1 * fR); if (d1 > Rm1) d1 = Rm1;
    unsigned d2 = (unsigned)(int)(u2 * fR); if (d2 > Rm1) d2 = Rm1;
    // uint32 wraparound matches reference (T = 2^19 divides 2^32 when masked)
    unsigned idx = (d0*RR + d1*R + d2) & M;
    xp[p] = tb[idx];                   // bf16x2, stored verbatim
  }
}

// ---------------- Stage 2: streaming MFMA MLP ----------------
__global__ __launch_bounds__(256, 4) void mlp_kernel(
    const unsigned* __restrict__ xw,
    const float* __restrict__ b1, const float* __restrict__ b2,
    const short* __restrict__ w1p, const short* __restrict__ w2p,
    float* __restrict__ out)
{
  const int l = threadIdx.x & 63;
  const int g = l >> 4;
  const int c = l & 15;
  const int w = threadIdx.x >> 6;

  __shared__ float obuf[4][16][68];   // per-wave transpose buffer

  bf16x8 w1f[8];
#pragma unroll
  for (int t = 0; t < 8; ++t)
    w1f[t] = *(const bf16x8*)(w1p + (size_t)(t*64 + l)*8);

  const int base = blockIdx.x * 4 + w;

  unsigned gx[4][4];
#pragma unroll
  for (int it = 0; it < 4; ++it) {
    int p = (base + it*16384)*16 + c;
#pragma unroll
    for (int q = 0; q < 4; ++q)
      gx[it][q] = xw[((size_t)(4*g + q) << 20) + p];
  }

#pragma unroll
  for (int it = 0; it < 4; ++it) {
    union { bf16x8 v; unsigned u[4]; } X;
#pragma unroll
    for (int q = 0; q < 4; ++q) X.u[q] = gx[it][q];
    bf16x8 xf = X.v;

    f32x4 h[8];
#pragma unroll
    for (int t = 0; t < 8; ++t) {
      h[t] = *(const f32x4*)(b1 + 16*t + 4*g);
      h[t] = __builtin_amdgcn_mfma_f32_16x16x32_bf16(w1f[t], xf, h[t], 0, 0, 0);
    }

    f32x4 o[4];
#pragma unroll
    for (int mt = 0; mt < 4; ++mt)
      o[mt] = *(const f32x4*)(b2 + 16*mt + 4*g);
#pragma unroll
    for (int ks = 0; ks < 4; ++ks) {
      bf16x8 bp;
#pragma unroll
      for (int j = 0; j < 8; ++j) {
        float v = h[2*ks + (j>>2)][j & 3];
        v = fmaxf(v, 0.0f);               // fused ReLU
        bp[j] = (__bf16)v;
      }
#pragma unroll
      for (int mt = 0; mt < 4; ++mt) {
        bf16x8 w2f = *(const bf16x8*)(w2p + (size_t)((mt*4 + ks)*64 + l)*8);
        o[mt] = __builtin_amdgcn_mfma_f32_16x16x32_bf16(w2f, bp, o[mt], 0, 0, 0);
      }
    }

    // LDS transpose -> each store instruction covers contiguous 1 KB.
    float (*ob)[68] = obuf[w];
#pragma unroll
    for (int mt = 0; mt < 4; ++mt)
      *(f32x4*)&ob[c][16*mt + 4*g] = o[mt];
    asm volatile("s_waitcnt lgkmcnt(0)" ::: "memory");   // wave-local fence
    f32x4 v[4];
#pragma unroll
    for (int s = 0; s < 4; ++s)
      v[s] = *(const f32x4*)&ob[4*s + g][4*c];
    asm volatile("" ::: "memory");
    float* op = out + (size_t)(base + it*16384) * 1024;
#pragma unroll
    for (int s = 0; s < 4; ++s)
      *(f32x4*)(op + (4*s + g)*64 + 4*c) = v[s];   // plain stores

    if (it < 3) asm volatile("s_waitcnt lgkmcnt(0)" ::: "memory");
  }
}

// ---------------- R1 fused kernel kept as fallback (ws too small) ----------
__global__ void prep_kernel(const float* __restrict__ W1, const float* __restrict__ W2,
                            short* __restrict__ w1p, short* __restrict__ w2p) {
  int tid = blockIdx.x * blockDim.x + threadIdx.x;   // 0..1535
  int l = tid & 63;
  int g = l >> 4;
  int c = l & 15;
  if (tid < 512) {
    int t = tid >> 6;
    bf16x8 v;
#pragma unroll
    for (int j = 0; j < 8; ++j)
      v[j] = (__bf16)W1[(8*g + j)*128 + 16*t + c];
    *(bf16x8*)(w1p + (size_t)(t*64 + l)*8) = v;
  } else if (tid < 1536) {
    int e = (tid - 512) >> 6;
    int mt = e >> 2, ks = e & 3;
    bf16x8 v;
#pragma unroll
    for (int j = 0; j < 8; ++j)
      v[j] = (__bf16)W2[(32*ks + 16*(j>>2) + 4*g + (j&3))*64 + 16*mt + c];
    *(bf16x8*)(w2p + (size_t)(e*64 + l)*8) = v;
  }
}

__global__ __launch_bounds__(256, 3) void hashgrid_mlp_kernel(
    const float* __restrict__ coords, const float* __restrict__ tables,
    const float* __restrict__ b1, const float* __restrict__ b2,
    const short* __restrict__ w1p, const short* __restrict__ w2p,
    float* __restrict__ out, int stride)
{
  const int l = threadIdx.x & 63;
  const int g = l >> 4;
  const int c = l & 15;

  unsigned Rq[4], RRq[4], Mq[4]; float fRq[4];
#pragma unroll
  for (int q = 0; q < 4; ++q) {
    int lv = 4*g + q;
    unsigned R = kRES[lv];
    Rq[q] = R; RRq[q] = R*R; fRq[q] = (float)R;
    Mq[q] = (lv >= 6) ? 0x7FFFFu : 0xFFFFFFFFu;
  }
  const float* tb = tables + ((size_t)g << 22);

  bf16x8 w1f[8];
#pragma unroll
  for (int t = 0; t < 8; ++t)
    w1f[t] = *(const bf16x8*)(w1p + (size_t)(t*64 + l)*8);

  f32x2 gx[4];
  auto prefetch = [&](int tile) {
    int p = tile*16 + c;
    float u0 = (coords[3*p+0] + 1.0f) * 0.5f;
    float u1 = (coords[3*p+1] + 1.0f) * 0.5f;
    float u2 = (coords[3*p+2] + 1.0f) * 0.5f;
#pragma unroll
    for (int q = 0; q < 4; ++q) {
      unsigned Rm1 = Rq[q] - 1u;
      unsigned d0 = (unsigned)(int)(u0 * fRq[q]); if (d0 > Rm1) d0 = Rm1;
      unsigned d1 = (unsigned)(int)(u1 * fRq[q]); if (d1 > Rm1) d1 = Rm1;
      unsigned d2 = (unsigned)(int)(u2 * fRq[q]); if (d2 > Rm1) d2 = Rm1;
      unsigned idx = (d0*RRq[q] + d1*Rq[q] + d2) & Mq[q];
      gx[q] = *(const f32x2*)(tb + ((size_t)q << 20) + (size_t)idx*2u);
    }
  };

  int tile = blockIdx.x * 4 + (threadIdx.x >> 6);
  prefetch(tile);
  while (true) {
    bf16x8 xf;
#pragma unroll
    for (int q = 0; q < 4; ++q) {
      xf[2*q]   = (__bf16)gx[q].x;
      xf[2*q+1] = (__bf16)gx[q].y;
    }
    int cur = tile;
    tile += stride;
    if (tile < NTILES) prefetch(tile);

    f32x4 h[8];
#pragma unroll
    for (int t = 0; t < 8; ++t) {
      h[t] = *(const f32x4*)(b1 + 16*t + 4*g);
      h[t] = __builtin_amdgcn_mfma_f32_16x16x32_bf16(w1f[t], xf, h[t], 0, 0, 0);
    }

    f32x4 o[4];
#pragma unroll
    for (int mt = 0; mt < 4; ++mt)
      o[mt] = *(const f32x4*)(b2 + 16*mt + 4*g);
#pragma unroll
    for (int ks = 0; ks < 4; ++ks) {
      bf16x8 bp;
#pragma unroll
      for (int j = 0; j < 8; ++j) {
        float v = h[2*ks + (j>>2)][j & 3];
        v = fmaxf(v, 0.0f);
        bp[j] = (__bf16)v;
      }
#pragma unroll
      for (int mt = 0; mt < 4; ++mt) {
        bf16x8 w2f = *(const bf16x8*)(w2p + (size_t)((mt*4 + ks)*64 + l)*8);
        o[mt] = __builtin_amdgcn_mfma_f32_16x16x32_bf16(w2f, bp, o[mt], 0, 0, 0);
      }
    }

    float* op = out + (size_t)(cur*16 + c)*64 + 4*g;
#pragma unroll
    for (int mt = 0; mt < 4; ++mt)
      *(f32x4*)(op + 16*mt) = o[mt];

    if (tile >= NTILES) break;
  }
}

extern "C" void kernel_launch(void* const* d_in, const int* in_sizes, int n_in,
                              void* d_out, int out_size, void* d_ws, size_t ws_size,
                              hipStream_t stream) {
  const float* coords = (const float*)d_in[0];
  const float* tables = (const float*)d_in[1];
  const float* W1     = (const float*)d_in[2];
  const float* b1     = (const float*)d_in[3];
  const float* W2     = (const float*)d_in[4];
  const float* b2     = (const float*)d_in[5];
  float* out = (float*)d_out;

  short* w1p = (short*)d_ws;                       // 8 KB
  short* w2p = w1p + 4096;                         // 16 KB (ends at 24 KB)

  const size_t XW_OFF  = 32*1024;
  const size_t XW_SZ   = (size_t)NPTS * 16 * 4;    // 64 MB
  const size_t TB2_SZ  = (size_t)16 * 524288 * 4;  // 32 MB
  const size_t need = XW_OFF + XW_SZ + TB2_SZ;

  if (ws_size >= need) {
    unsigned* xw  = (unsigned*)((char*)d_ws + XW_OFF);
    unsigned* tb2 = (unsigned*)((char*)d_ws + XW_OFF + XW_SZ);
    tconv_prep_kernel<<<8198, 256, 0, stream>>>(tables, W1, W2, tb2, w1p, w2p);
    gather_kernel<<<16384, 256, 0, stream>>>(coords, tb2, xw);
    mlp_kernel<<<4096, 256, 0, stream>>>(xw, b1, b2, w1p, w2p, out);
  } else {
    prep_kernel<<<6, 256, 0, stream>>>(W1, W2, w1p, w2p);
    const int blocks = 2048;
    hashgrid_mlp_kernel<<<blocks, 256, 0, stream>>>(coords, tables, b1, b2,
                                                    w1p, w2p, out, blocks*4);
  }
}